// Round 11
// baseline (2240.552 us; speedup 1.0000x reference)
//
#include <hip/hip_runtime.h>

#define Bsz  256
#define Tlen 2048
#define Hdim 128

typedef __fp16 hf2 __attribute__((ext_vector_type(2)));

__device__ __forceinline__ float sigmoidf_(float v) { return 1.0f / (1.0f + __expf(-v)); }
__device__ __forceinline__ float tanhf_(float v)    { return 1.0f - 2.0f / (__expf(2.0f * v) + 1.0f); }

// DPP butterfly add over groups of 8 consecutive lanes — pure VALU pipe.
template <int CTRL>
__device__ __forceinline__ float dpp_add(float v) {
    int t = __builtin_amdgcn_update_dpp(0, __float_as_int(v), CTRL, 0xf, 0xf, true);
    return v + __int_as_float(t);
}
// 0xB1 quad_perm xor1, 0x4E quad_perm xor2, 0x141 row_half_mirror.
// Full 8-lane allreduce. HW-verified R4/R7/R10 (passed).
__device__ __forceinline__ float red8(float v) {
    v = dpp_add<0xB1>(v);
    v = dpp_add<0x4E>(v);
    v = dpp_add<0x141>(v);
    return v;
}

__device__ __forceinline__ hf2 bch(float f) { return __builtin_bit_cast(hf2, f); }
__device__ __forceinline__ float pkh(float a, float b) {
    return __builtin_bit_cast(float, __builtin_amdgcn_cvt_pkrtz(a, b));
}

// dot of one 16-value row strip (two float4 of packed f16) against h chunk
#define DOTC(acc, lo, hi) do {                                       \
    acc = __builtin_amdgcn_fdot2(bch(lo.x), h0, acc, false);         \
    acc = __builtin_amdgcn_fdot2(bch(lo.y), h1, acc, false);         \
    acc = __builtin_amdgcn_fdot2(bch(lo.z), h2, acc, false);         \
    acc = __builtin_amdgcn_fdot2(bch(lo.w), h3, acc, false);         \
    acc = __builtin_amdgcn_fdot2(bch(hi.x), h4, acc, false);         \
    acc = __builtin_amdgcn_fdot2(bch(hi.y), h5, acc, false);         \
    acc = __builtin_amdgcn_fdot2(bch(hi.z), h6, acc, false);         \
    acc = __builtin_amdgcn_fdot2(bch(hi.w), h7, acc, false); } while (0)

// grid = 256 blocks (one batch row per block), block = 512 threads (8 waves).
// thread t: kc = t & 7 -> k-chunk [kc*16, kc*16+16)
//           rg = t >> 3 -> unit pair u0 = 2*rg, u0+1; owns Whh rows
//           {u0,u0+1} x {r,z,n} over its k-chunk, stored as packed f16 in an
//           EXPLICIT per-thread LDS strip (12 x 16 B, 13-float4 padded stride:
//           lane bases l*52%32 = {0,20,8,28,16,4,24,12} -> each 8-lane group's
//           b128 reads tile all 32 banks exactly once, conflict-free).
// Weights stream LDS->VGPR every step (~100 KB/step/CU at 85-128 B/cyc) —
// deterministic, replacing the L2/scratch refetch (~56 B/cyc) that pinned
// R1-R10 at ~2 ms (compiler refuses arch-VGPR residency; R7-R10 evidence).
__global__ __launch_bounds__(512)
void rnn_imp_kernel(const float* __restrict__ x,     // [B, T] (I=1)
                    const float* __restrict__ Wih,   // [384]
                    const float* __restrict__ Whh,   // [384, 128]
                    const float* __restrict__ bih,   // [384]
                    const float* __restrict__ bhh,   // [384]
                    const float* __restrict__ Wfc,   // [128]
                    const float* __restrict__ bfc,   // [1]
                    float* __restrict__ out_newin,   // [T, B]
                    float* __restrict__ out_pred)    // [B, T-1]
{
    __shared__ __align__(16) float  x_s[Tlen + 4];
    __shared__ __align__(16) hf2    h16_s[2][160];     // 8 chunks x 20 hf2 (8 data + 12 pad)
    __shared__ __align__(16) float4 w_lds[512][13];    // per-thread strip, 106496 B
    __shared__ __align__(16) float4 wfc_lds[16];       // 8 kc-chunks x 2

    const int tid = threadIdx.x;
    const int b   = blockIdx.x;
    const int kc  = tid & 7;
    const int rg  = tid >> 3;
    const int u0  = rg * 2;

    // stage x row (coalesced) and zero h buffer 0
    for (int i = tid; i < Tlen; i += 512) x_s[i] = x[b * Tlen + i];
    if (tid < 160) h16_s[0][tid] = hf2{(__fp16)0, (__fp16)0};

    // stage weight strips: 6 rows x 16 f32 -> f16 -> 12 float4 chunks
#pragma unroll
    for (int g = 0; g < 3; ++g)
#pragma unroll
        for (int un = 0; un < 2; ++un) {
            const float4* wp = (const float4*)(Whh + (g * Hdim + u0 + un) * Hdim + kc * 16);
            float4 A = wp[0], B4 = wp[1], C4 = wp[2], D4 = wp[3];
            float4 lo, hi;
            lo.x = pkh(A.x, A.y);  lo.y = pkh(A.z, A.w);
            lo.z = pkh(B4.x, B4.y); lo.w = pkh(B4.z, B4.w);
            hi.x = pkh(C4.x, C4.y); hi.y = pkh(C4.z, C4.w);
            hi.z = pkh(D4.x, D4.y); hi.w = pkh(D4.z, D4.w);
            const int rowid = g * 2 + un;
            w_lds[tid][rowid * 2 + 0] = lo;
            w_lds[tid][rowid * 2 + 1] = hi;
        }
    if (tid < 8) {
        const float4* fp = (const float4*)(Wfc + tid * 16);
        float4 A = fp[0], B4 = fp[1], C4 = fp[2], D4 = fp[3];
        float4 lo, hi;
        lo.x = pkh(A.x, A.y);  lo.y = pkh(A.z, A.w);
        lo.z = pkh(B4.x, B4.y); lo.w = pkh(B4.z, B4.w);
        hi.x = pkh(C4.x, C4.y); hi.y = pkh(C4.z, C4.w);
        hi.z = pkh(D4.x, D4.y); hi.w = pkh(D4.z, D4.w);
        wfc_lds[tid * 2 + 0] = lo;
        wfc_lds[tid * 2 + 1] = hi;
    }

    // per-unit gate constants (identical across the 8 lanes of a group)
    const float wih_r0 = Wih[u0],     wih_r1 = Wih[u0 + 1];
    const float wih_z0 = Wih[u0+128], wih_z1 = Wih[u0 + 129];
    const float wih_n0 = Wih[u0+256], wih_n1 = Wih[u0 + 257];
    const float bb_r0 = bih[u0]     + bhh[u0],       bb_r1 = bih[u0+1]   + bhh[u0+1];
    const float bb_z0 = bih[u0+128] + bhh[u0+128],   bb_z1 = bih[u0+129] + bhh[u0+129];
    const float bi_n0 = bih[u0+256], bi_n1 = bih[u0 + 257];
    const float bh_n0 = bhh[u0+256], bh_n1 = bhh[u0 + 257];
    const float bfc0  = bfc[0];
    float h_old0 = 0.0f, h_old1 = 0.0f;

    const int rb = kc * 20;                             // h chunk base (hf2), 16B-aligned
    const int pw = (u0 >> 4) * 20 + ((u0 >> 1) & 7);    // h write slot

    __syncthreads();

#pragma unroll 1
    for (int t = 0; t < Tlen; ++t) {
        const hf2* hb = h16_s[t & 1];
        hf2*       hw = h16_s[(t + 1) & 1];
        float xt = x_s[t];

        // weight strip pointer made opaque each iteration: the 12 ds_reads
        // cannot be hoisted/promoted to registers (the R1-R10 trap).
        const float4* wt = &w_lds[tid][0];
        asm volatile("" : "+v"(wt));
        float4 wA0 = wt[0],  wA1 = wt[1],  wB0 = wt[2],  wB1 = wt[3],
               wC0 = wt[4],  wC1 = wt[5],  wD0 = wt[6],  wD1 = wt[7],
               wE0 = wt[8],  wE1 = wt[9],  wF0 = wt[10], wF1 = wt[11];
        const float4* fq = (const float4*)&wfc_lds[kc * 2];
        float4 f0 = fq[0], f1 = fq[1];

        // h chunk: 2x ds_read_b128 (16 packed values), broadcast across rg
        const float4* hp = (const float4*)(hb + rb);
        float4 qa = hp[0], qb = hp[1];
        hf2 h0 = bch(qa.x), h1 = bch(qa.y), h2 = bch(qa.z), h3 = bch(qa.w),
            h4 = bch(qb.x), h5 = bch(qb.y), h6 = bch(qb.z), h7 = bch(qb.w);

        float ar0 = 0.f, ar1 = 0.f, az0 = 0.f, az1 = 0.f,
              an0 = 0.f, an1 = 0.f, axp = 0.f;
        DOTC(axp, f0, f1);                  // xp first: xh feeds the gate chain
        DOTC(ar0, wA0, wA1); DOTC(ar1, wB0, wB1);
        DOTC(az0, wC0, wC1); DOTC(az1, wD0, wD1);
        DOTC(an0, wE0, wE1); DOTC(an1, wF0, wF1);

        // 8-lane DPP butterfly; every lane ends with the full sums
        float xp  = red8(axp);
        float gr0 = red8(ar0);
        float gr1 = red8(ar1);
        float gz0 = red8(az0);
        float gz1 = red8(az1);
        float gn0 = red8(an0);
        float gn1 = red8(an1);

        float xh  = xp + bfc0;
        float cur = ((xt == 128.0f) && (t != 0)) ? xh : xt;

        float r0 = sigmoidf_(wih_r0 * cur + bb_r0 + gr0);
        float z0 = sigmoidf_(wih_z0 * cur + bb_z0 + gz0);
        float n0 = tanhf_(wih_n0 * cur + bi_n0 + r0 * (gn0 + bh_n0));
        float hn0 = (1.0f - z0) * n0 + z0 * h_old0;

        float r1 = sigmoidf_(wih_r1 * cur + bb_r1 + gr1);
        float z1 = sigmoidf_(wih_z1 * cur + bb_z1 + gz1);
        float n1 = tanhf_(wih_n1 * cur + bi_n1 + r1 * (gn1 + bh_n1));
        float hn1 = (1.0f - z1) * n1 + z1 * h_old1;

        h_old0 = hn0; h_old1 = hn1;

        if (kc == 0) {
            hw[pw] = __builtin_amdgcn_cvt_pkrtz(hn0, hn1);
        }
        if (tid == 0) {
            out_newin[t * Bsz + b] = cur;
            if (t != 0) out_pred[b * (Tlen - 1) + (t - 1)] = xh;
        }
        __syncthreads();
    }
}

extern "C" void kernel_launch(void* const* d_in, const int* in_sizes, int n_in,
                              void* d_out, int out_size, void* d_ws, size_t ws_size,
                              hipStream_t stream) {
    const float* x   = (const float*)d_in[0];
    const float* Wih = (const float*)d_in[1];
    const float* Whh = (const float*)d_in[2];
    const float* bih = (const float*)d_in[3];
    const float* bhh = (const float*)d_in[4];
    const float* Wfc = (const float*)d_in[5];
    const float* bfc = (const float*)d_in[6];

    float* out_newin = (float*)d_out;                 // [T*B] = 524288
    float* out_pred  = out_newin + Tlen * Bsz;        // [B*(T-1)] = 524032

    rnn_imp_kernel<<<Bsz, 512, 0, stream>>>(x, Wih, Whh, bih, bhh, Wfc, bfc,
                                            out_newin, out_pred);
}

// Round 12
// 1336.713 us; speedup vs baseline: 1.6762x; 1.6762x over previous
//
#include <hip/hip_runtime.h>

#define Bsz  256
#define Tlen 2048
#define Hdim 128

typedef __fp16 hf2 __attribute__((ext_vector_type(2)));

// Raw-HW transcendentals (VOP1, 1 instr each, ~1 ulp) — avoids the precise
// IEEE div sequence (v_div_scale/fmas/fixup ~10 instrs + long chain) and any
// precise-ocml exp that the default (no -ffast-math) build emits. R11 evidence:
// duration x VALUBusy constant ~1540 us across R3-R11 -> gate math is the
// invariant VALU hog (6 div + 6 exp per thread per step, all 512 threads).
__device__ __forceinline__ float fexp2_(float x) {
    float r; asm("v_exp_f32 %0, %1" : "=v"(r) : "v"(x)); return r;
}
__device__ __forceinline__ float frcp_(float x) {
    float r; asm("v_rcp_f32 %0, %1" : "=v"(r) : "v"(x)); return r;
}
// sigmoid(v) = 1/(1+exp(-v)) = rcp(1 + 2^(-v*log2e))
__device__ __forceinline__ float sigmoidf_(float v) {
    return frcp_(1.0f + fexp2_(v * -1.44269504f));
}
// tanh(v) = 1 - 2/(exp(2v)+1) = 1 - 2*rcp(2^(v*2*log2e)+1)
__device__ __forceinline__ float tanhf_(float v) {
    return 1.0f - 2.0f * frcp_(fexp2_(v * 2.88539008f) + 1.0f);
}

// Pin a packed-f16 pair into a VGPR (opaque to remat/sinking).
__device__ __forceinline__ void pinh(hf2& v) { asm volatile("" : "+v"(v)); }

// DPP butterfly add over groups of 8 consecutive lanes — pure VALU pipe.
template <int CTRL>
__device__ __forceinline__ float dpp_add(float v) {
    int t = __builtin_amdgcn_update_dpp(0, __float_as_int(v), CTRL, 0xf, 0xf, true);
    return v + __int_as_float(t);
}
// 0xB1 quad_perm xor1, 0x4E quad_perm xor2, 0x141 row_half_mirror.
// Full 8-lane allreduce. HW-verified R4/R7/R10 (passed).
__device__ __forceinline__ float red8(float v) {
    v = dpp_add<0xB1>(v);
    v = dpp_add<0x4E>(v);
    v = dpp_add<0x141>(v);
    return v;
}

// --- named packed-f16 weight strips (16 f32 -> 8 packed VGPRs each) ---
#define DECL8(p) hf2 p##0, p##1, p##2, p##3, p##4, p##5, p##6, p##7
#define LOAD8H(p, ptr) do {                                          \
    const float4* _q = (const float4*)(ptr);                         \
    float4 _a = _q[0], _b = _q[1], _c = _q[2], _d = _q[3];           \
    p##0 = __builtin_amdgcn_cvt_pkrtz(_a.x, _a.y);                   \
    p##1 = __builtin_amdgcn_cvt_pkrtz(_a.z, _a.w);                   \
    p##2 = __builtin_amdgcn_cvt_pkrtz(_b.x, _b.y);                   \
    p##3 = __builtin_amdgcn_cvt_pkrtz(_b.z, _b.w);                   \
    p##4 = __builtin_amdgcn_cvt_pkrtz(_c.x, _c.y);                   \
    p##5 = __builtin_amdgcn_cvt_pkrtz(_c.z, _c.w);                   \
    p##6 = __builtin_amdgcn_cvt_pkrtz(_d.x, _d.y);                   \
    p##7 = __builtin_amdgcn_cvt_pkrtz(_d.z, _d.w); } while (0)
#define PINH8(p) do { pinh(p##0); pinh(p##1); pinh(p##2); pinh(p##3); \
                      pinh(p##4); pinh(p##5); pinh(p##6); pinh(p##7); } while (0)
// 8 chained v_dot2_f32_f16: acc += sum_j p_j . h_j  (f32 accumulate)
#define DOT8(acc, p) do {                                            \
    acc = __builtin_amdgcn_fdot2(p##0, h0, acc, false);              \
    acc = __builtin_amdgcn_fdot2(p##1, h1, acc, false);              \
    acc = __builtin_amdgcn_fdot2(p##2, h2, acc, false);              \
    acc = __builtin_amdgcn_fdot2(p##3, h3, acc, false);              \
    acc = __builtin_amdgcn_fdot2(p##4, h4, acc, false);              \
    acc = __builtin_amdgcn_fdot2(p##5, h5, acc, false);              \
    acc = __builtin_amdgcn_fdot2(p##6, h6, acc, false);              \
    acc = __builtin_amdgcn_fdot2(p##7, h7, acc, false); } while (0)

// grid = 256 blocks (one batch row per block), block = 512 threads (8 waves).
// thread t: kc = t & 7 -> k-chunk [kc*16, kc*16+16)
//           rg = t >> 3 -> unit pair u0 = 2*rg, u0+1; owns Whh rows
//           {u0,u0+1} x {r,z,n} over its k-chunk as packed f16.
// h lives in LDS as packed f16, chunk kc at hf2 index kc*12 (48B stride:
// 16B-aligned, banks kc*12%32 = {0,12,24,4,16,28,8,20} all distinct).
__global__ __launch_bounds__(512)
void rnn_imp_kernel(const float* __restrict__ x,     // [B, T] (I=1)
                    const float* __restrict__ Wih,   // [384]
                    const float* __restrict__ Whh,   // [384, 128]
                    const float* __restrict__ bih,   // [384]
                    const float* __restrict__ bhh,   // [384]
                    const float* __restrict__ Wfc,   // [128]
                    const float* __restrict__ bfc,   // [1]
                    float* __restrict__ out_newin,   // [T, B]
                    float* __restrict__ out_pred)    // [B, T-1]
{
    __shared__ __align__(16) float x_s[Tlen + 4];
    __shared__ __align__(16) hf2  h16_s[2][96];      // 8 chunks x (8 data + 4 pad)

    const int tid = threadIdx.x;
    const int b   = blockIdx.x;
    const int kc  = tid & 7;
    const int rg  = tid >> 3;
    const int u0  = rg * 2;

    // stage x row (coalesced) and zero h buffer 0
    for (int i = tid; i < Tlen; i += 512) x_s[i] = x[b * Tlen + i];
    if (tid < 96) h16_s[0][tid] = hf2{(__fp16)0, (__fp16)0};

    // weight strips -> packed f16 named scalars
    DECL8(wr0); DECL8(wr1); DECL8(wz0); DECL8(wz1); DECL8(wn0); DECL8(wn1); DECL8(wf);
    LOAD8H(wr0, Whh + (0 * Hdim + u0 + 0) * Hdim + kc * 16);
    LOAD8H(wr1, Whh + (0 * Hdim + u0 + 1) * Hdim + kc * 16);
    LOAD8H(wz0, Whh + (1 * Hdim + u0 + 0) * Hdim + kc * 16);
    LOAD8H(wz1, Whh + (1 * Hdim + u0 + 1) * Hdim + kc * 16);
    LOAD8H(wn0, Whh + (2 * Hdim + u0 + 0) * Hdim + kc * 16);
    LOAD8H(wn1, Whh + (2 * Hdim + u0 + 1) * Hdim + kc * 16);
    LOAD8H(wf,  Wfc + kc * 16);
    PINH8(wr0); PINH8(wr1); PINH8(wz0); PINH8(wz1); PINH8(wn0); PINH8(wn1); PINH8(wf);

    // per-unit gate constants (identical across the 8 lanes of a group)
    const float wih_r0 = Wih[u0],     wih_r1 = Wih[u0 + 1];
    const float wih_z0 = Wih[u0+128], wih_z1 = Wih[u0 + 129];
    const float wih_n0 = Wih[u0+256], wih_n1 = Wih[u0 + 257];
    const float bb_r0 = bih[u0]     + bhh[u0],       bb_r1 = bih[u0+1]   + bhh[u0+1];
    const float bb_z0 = bih[u0+128] + bhh[u0+128],   bb_z1 = bih[u0+129] + bhh[u0+129];
    const float bi_n0 = bih[u0+256], bi_n1 = bih[u0 + 257];
    const float bh_n0 = bhh[u0+256], bh_n1 = bhh[u0 + 257];
    const float bfc0  = bfc[0];
    float h_old0 = 0.0f, h_old1 = 0.0f;

    const int rbase = kc * 12;                              // hf2 chunk base
    const int pw    = (u0 >> 4) * 12 + ((u0 >> 1) & 7);     // hf2 write slot

    __syncthreads();

#pragma unroll 1
    for (int t = 0; t < Tlen; ++t) {
        const hf2* hb = h16_s[t & 1];
        hf2*       hw = h16_s[(t + 1) & 1];
        float xt = x_s[t];

        // h chunk: 2x ds_read_b128 of packed f16 (16 values)
        const float4* hp = (const float4*)(hb + rbase);
        float4 qa = hp[0], qb = hp[1];
        hf2 h0 = __builtin_bit_cast(hf2, qa.x), h1 = __builtin_bit_cast(hf2, qa.y),
            h2 = __builtin_bit_cast(hf2, qa.z), h3 = __builtin_bit_cast(hf2, qa.w),
            h4 = __builtin_bit_cast(hf2, qb.x), h5 = __builtin_bit_cast(hf2, qb.y),
            h6 = __builtin_bit_cast(hf2, qb.z), h7 = __builtin_bit_cast(hf2, qb.w);

        float ar0 = 0.f, ar1 = 0.f, az0 = 0.f, az1 = 0.f,
              an0 = 0.f, an1 = 0.f, axp = 0.f;
        DOT8(axp, wf);                  // xp first: xh feeds the gate chain
        DOT8(ar0, wr0); DOT8(ar1, wr1);
        DOT8(az0, wz0); DOT8(az1, wz1);
        DOT8(an0, wn0); DOT8(an1, wn1);

        // 8-lane DPP butterfly; every lane ends with the full sums
        float xp  = red8(axp);
        float gr0 = red8(ar0);
        float gr1 = red8(ar1);
        float gz0 = red8(az0);
        float gz1 = red8(az1);
        float gn0 = red8(an0);
        float gn1 = red8(an1);

        float xh  = xp + bfc0;
        float cur = ((xt == 128.0f) && (t != 0)) ? xh : xt;

        float r0 = sigmoidf_(wih_r0 * cur + bb_r0 + gr0);
        float z0 = sigmoidf_(wih_z0 * cur + bb_z0 + gz0);
        float n0 = tanhf_(wih_n0 * cur + bi_n0 + r0 * (gn0 + bh_n0));
        float hn0 = (1.0f - z0) * n0 + z0 * h_old0;

        float r1 = sigmoidf_(wih_r1 * cur + bb_r1 + gr1);
        float z1 = sigmoidf_(wih_z1 * cur + bb_z1 + gz1);
        float n1 = tanhf_(wih_n1 * cur + bi_n1 + r1 * (gn1 + bh_n1));
        float hn1 = (1.0f - z1) * n1 + z1 * h_old1;

        h_old0 = hn0; h_old1 = hn1;

        if (kc == 0) {
            hw[pw] = __builtin_amdgcn_cvt_pkrtz(hn0, hn1);
        }
        if (tid == 0) {
            out_newin[t * Bsz + b] = cur;
            if (t != 0) out_pred[b * (Tlen - 1) + (t - 1)] = xh;
        }
        __syncthreads();
    }
}

extern "C" void kernel_launch(void* const* d_in, const int* in_sizes, int n_in,
                              void* d_out, int out_size, void* d_ws, size_t ws_size,
                              hipStream_t stream) {
    const float* x   = (const float*)d_in[0];
    const float* Wih = (const float*)d_in[1];
    const float* Whh = (const float*)d_in[2];
    const float* bih = (const float*)d_in[3];
    const float* bhh = (const float*)d_in[4];
    const float* Wfc = (const float*)d_in[5];
    const float* bfc = (const float*)d_in[6];

    float* out_newin = (float*)d_out;                 // [T*B] = 524288
    float* out_pred  = out_newin + Tlen * Bsz;        // [B*(T-1)] = 524032

    rnn_imp_kernel<<<Bsz, 512, 0, stream>>>(x, Wih, Whh, bih, bhh, Wfc, bfc,
                                            out_newin, out_pred);
}